// Round 4
// baseline (1321.417 us; speedup 1.0000x reference)
//
#include <hip/hip_runtime.h>

#define BB 2048
#define TT 2048
#define HH 16

__device__ __forceinline__ float rl(float v, int l) {
    return __int_as_float(__builtin_amdgcn_readlane(__float_as_int(v), l));
}
__device__ __forceinline__ float bperm(int byteaddr, float v) {
    return __int_as_float(__builtin_amdgcn_ds_bpermute(byteaddr, __float_as_int(v)));
}
__device__ __forceinline__ float fexp2(float x) {
#if __has_builtin(__builtin_amdgcn_exp2f)
    return __builtin_amdgcn_exp2f(x);
#else
    return exp2f(x);
#endif
}
__device__ __forceinline__ float frcp(float x) {
#if __has_builtin(__builtin_amdgcn_rcpf)
    return __builtin_amdgcn_rcpf(x);
#else
    return 1.0f / x;
#endif
}

#define L2E  1.442695041f
#define L2E2 2.885390082f

#if __has_builtin(__builtin_amdgcn_permlane32_swap) && __has_builtin(__builtin_amdgcn_permlane16_swap)
#define USE_PERMLANE 1
#endif

// Gate gather: act lane L = gate row L (0-15=i, 16-31=f, 32-47=g, 48-63=o).
// permlane32_swap(a,a) -> ret0=[i,f,i,f], ret1=[g,o,g,o] (quarters of 16 lanes).
// permlane16_swap(x,x) on each -> fully replicated [i,i,i,i],[f,f,f,f],...
// This dataflow was validated by round 3's correct 2047-step trajectory; we now
// use the compiler-modeled builtins instead of hand-rolled 2-operand asm.
__device__ __forceinline__ void gates4(float act, int ai,
                                       float& i_, float& f_, float& g_, float& o_) {
#ifdef USE_PERMLANE
    unsigned a = __float_as_uint(act);
    auto pq  = __builtin_amdgcn_permlane32_swap(a, a, false, false);
    auto if2 = __builtin_amdgcn_permlane16_swap(pq[0], pq[0], false, false);
    auto go2 = __builtin_amdgcn_permlane16_swap(pq[1], pq[1], false, false);
    i_ = __uint_as_float(if2[0]); f_ = __uint_as_float(if2[1]);
    g_ = __uint_as_float(go2[0]); o_ = __uint_as_float(go2[1]);
#else
    i_ = bperm(ai, act); f_ = bperm(ai + 64, act);
    g_ = bperm(ai + 128, act); o_ = bperm(ai + 192, act);
#endif
}

// 1 wave = 1 batch row; lane = gate row; 2048 waves = 2 waves/SIMD.
// Iteration k runs layer0@t=k+1 and layer1@t=k as two independent chains.
// Steady-state loop is DS/VMEM-light: gate gather on the VALU pipe (permlane),
// h broadcast via v_readlane -> SGPRs, weights pinned in VGPRs (opaque asm
// prevents per-step global re-loads; VGPR_Count 40/60 in prior rounds proved
// the compiler was re-fetching all 48 weight floats every timestep).
__global__ __launch_bounds__(256, 2) void lstm2_kernel(
    const float* __restrict__ x,     // [B,T,1]
    const float* __restrict__ h0in,  // [2,B,16]
    const float* __restrict__ c0in,  // [2,B,16]
    const float* __restrict__ Wih0,  // [64,1]
    const float* __restrict__ Whh0,  // [64,16]
    const float* __restrict__ bih0,  // [64]
    const float* __restrict__ bhh0,  // [64]
    const float* __restrict__ Wih1,  // [64,16]
    const float* __restrict__ Whh1,  // [64,16]
    const float* __restrict__ bih1,  // [64]
    const float* __restrict__ bhh1,  // [64]
    float* __restrict__ out)         // [B*T*16] ++ hN[2,B,16] ++ cN[2,B,16]
{
    const int lane = threadIdx.x & 63;
    const int wid  = threadIdx.x >> 6;
    const int b    = blockIdx.x * 4 + wid;
    const int j    = lane & 15;

    // per-lane weight rows (lane = gate row)
    float w0[16], wi1[16], w1[16];
#pragma unroll
    for (int k = 0; k < 16; ++k) {
        w0[k]  = Whh0[lane * 16 + k];
        wi1[k] = Wih1[lane * 16 + k];
        w1[k]  = Whh1[lane * 16 + k];
    }
    float wx    = Wih0[lane];
    float bias0 = bih0[lane] + bhh0[lane];
    float bias1 = bih1[lane] + bhh1[lane];

    // Pin in VGPRs: opaque results cannot be rematerialized by re-loading.
#pragma unroll
    for (int k = 0; k < 16; ++k) {
        asm("" : "+v"(w0[k]), "+v"(wi1[k]), "+v"(w1[k]));
    }
    asm("" : "+v"(wx), "+v"(bias0), "+v"(bias1));

    // state, replicated across all 4 lane-groups (every lane holds unit j)
    float h0v = h0in[0 * BB * HH + b * HH + j];
    float c0  = c0in[0 * BB * HH + b * HH + j];
    float h1v = h0in[1 * BB * HH + b * HH + j];
    float c1  = c0in[1 * BB * HH + b * HH + j];

    // wave-uniform broadcast copies of h0/h1 (live in SGPRs)
    float sh0[16], sh1[16];
#pragma unroll
    for (int k = 0; k < 16; ++k) { sh0[k] = rl(h0v, k); sh1[k] = rl(h1v, k); }

    // activation selector: rows 0-31 (i,f) sigmoid, 32-47 (g) tanh, 48-63 (o) sigmoid
    const bool is_tanh = ((lane >> 4) == 2);
    const float Aa = is_tanh ? 2.0f  : 1.0f;
    const float Bb = is_tanh ? -L2E2 : -L2E;
    const float Cc = is_tanh ? -1.0f : 0.0f;
    const int ai = j * 4;
    const int phase = lane >> 4;
    float hist = 0.0f;

    const float* xp = x + (size_t)b * TT;
    float*       po = out + (size_t)b * TT * HH;

    // ---- prologue: layer 0 @ t=0 ----
    {
        float xt = xp[0];
        float A0 = fmaf(xt, wx, bias0), A1 = 0.0f;   // even-k / odd-k chains
#pragma unroll
        for (int k = 0; k < 16; k += 2) {
            A0 = fmaf(sh0[k],     w0[k],     A0);
            A1 = fmaf(sh0[k + 1], w0[k + 1], A1);
        }
        float acc = A0 + A1;
        float act = fmaf(Aa, frcp(1.0f + fexp2(Bb * acc)), Cc);
        float i_, f_, g_, o_;
        gates4(act, ai, i_, f_, g_, o_);
        c0  = fmaf(f_, c0, i_ * g_);
        h0v = o_ * fmaf(2.0f, frcp(1.0f + fexp2(-L2E2 * c0)), -1.0f);
#pragma unroll
        for (int k = 0; k < 16; ++k) sh0[k] = rl(h0v, k);
    }

    // x staging, double-buffered one 64-block ahead
    int xnext = __float_as_int(xp[1 + lane]);
    int xcur  = 0;

#pragma unroll 4
    for (int k = 0; k < TT - 1; ++k) {
        if ((k & 63) == 0) {
            xcur = xnext;
            int idx = k + 65 + lane; if (idx > TT - 1) idx = TT - 1;
            xnext = __float_as_int(xp[idx]);
        }
        float xt = __int_as_float(__builtin_amdgcn_readlane(xcur, k & 63));

        // ---- chain A: layer 0 @ t=k+1; chain B: layer 1 @ t=k (independent) ----
        float A0 = fmaf(xt, wx, bias0), A1 = 0.0f;
        float B0 = bias1, B1 = 0.0f;
#pragma unroll
        for (int kk = 0; kk < 16; kk += 2) {
            A0 = fmaf(sh0[kk],     w0[kk],      A0);
            A1 = fmaf(sh0[kk + 1], w0[kk + 1],  A1);
            B0 = fmaf(sh0[kk],     wi1[kk],     B0);
            B1 = fmaf(sh0[kk + 1], wi1[kk + 1], B1);
        }
#pragma unroll
        for (int kk = 0; kk < 16; kk += 2) {
            B0 = fmaf(sh1[kk],     w1[kk],     B0);
            B1 = fmaf(sh1[kk + 1], w1[kk + 1], B1);
        }
        float acc0 = A0 + A1;
        float acc1 = B0 + B1;
        float act0 = fmaf(Aa, frcp(1.0f + fexp2(Bb * acc0)), Cc);
        float act1 = fmaf(Aa, frcp(1.0f + fexp2(Bb * acc1)), Cc);

        float i0, f0, g0, o0, i1, f1, g1, o1;
        gates4(act0, ai, i0, f0, g0, o0);
        gates4(act1, ai, i1, f1, g1, o1);

        c0  = fmaf(f0, c0, i0 * g0);
        h0v = o0 * fmaf(2.0f, frcp(1.0f + fexp2(-L2E2 * c0)), -1.0f);
        c1  = fmaf(f1, c1, i1 * g1);
        h1v = o1 * fmaf(2.0f, frcp(1.0f + fexp2(-L2E2 * c1)), -1.0f);

        // refresh h broadcasts (SGPRs) for next iteration's dots
#pragma unroll
        for (int kk = 0; kk < 16; ++kk) { sh0[kk] = rl(h0v, kk); sh1[kk] = rl(h1v, kk); }

        // out row k = h1 after step k; batch 4 rows per coalesced store
        hist = (phase == (k & 3)) ? h1v : hist;
        if ((k & 3) == 3) po[(size_t)(k - 3) * HH + lane] = hist;
    }

    // ---- epilogue: layer 1 @ t=TT-1 (consumes sh0 = bcast(h0_{T-1})) ----
    {
        float B0 = bias1, B1 = 0.0f;
#pragma unroll
        for (int kk = 0; kk < 16; kk += 2) {
            B0 = fmaf(sh0[kk],     wi1[kk],     B0);
            B1 = fmaf(sh0[kk + 1], wi1[kk + 1], B1);
        }
#pragma unroll
        for (int kk = 0; kk < 16; kk += 2) {
            B0 = fmaf(sh1[kk],     w1[kk],     B0);
            B1 = fmaf(sh1[kk + 1], w1[kk + 1], B1);
        }
        float acc1 = B0 + B1;
        float act1 = fmaf(Aa, frcp(1.0f + fexp2(Bb * acc1)), Cc);
        float i1, f1, g1, o1;
        gates4(act1, ai, i1, f1, g1, o1);
        c1  = fmaf(f1, c1, i1 * g1);
        h1v = o1 * fmaf(2.0f, frcp(1.0f + fexp2(-L2E2 * c1)), -1.0f);
        hist = (phase == 3) ? h1v : hist;
        po[(size_t)(TT - 4) * HH + lane] = hist;  // rows 2044..2047
    }

    // final states: hN = [h_l0, h_l1], cN likewise. All 64 lanes write; the 4
    // lane-groups hold bitwise-identical replicated state, so the redundant
    // same-address stores are benign (no divergent guard needed).
    {
        const size_t offH = (size_t)BB * TT * HH;
        const size_t offC = offH + (size_t)2 * BB * HH;
        out[offH + 0 * BB * HH + b * HH + j] = h0v;
        out[offH + 1 * BB * HH + b * HH + j] = h1v;
        out[offC + 0 * BB * HH + b * HH + j] = c0;
        out[offC + 1 * BB * HH + b * HH + j] = c1;
    }
}

extern "C" void kernel_launch(void* const* d_in, const int* in_sizes, int n_in,
                              void* d_out, int out_size, void* d_ws, size_t ws_size,
                              hipStream_t stream) {
    const float* x    = (const float*)d_in[0];
    const float* h0   = (const float*)d_in[1];
    const float* c0   = (const float*)d_in[2];
    const float* Wih0 = (const float*)d_in[3];
    const float* Whh0 = (const float*)d_in[4];
    const float* bih0 = (const float*)d_in[5];
    const float* bhh0 = (const float*)d_in[6];
    const float* Wih1 = (const float*)d_in[7];
    const float* Whh1 = (const float*)d_in[8];
    const float* bih1 = (const float*)d_in[9];
    const float* bhh1 = (const float*)d_in[10];
    float* out = (float*)d_out;

    dim3 grid(BB / 4);   // 512 blocks x 4 waves = 2048 waves, one per batch row
    dim3 block(256);
    lstm2_kernel<<<grid, block, 0, stream>>>(x, h0, c0, Wih0, Whh0, bih0, bhh0,
                                             Wih1, Whh1, bih1, bhh1, out);
}